// Round 1
// baseline (781.003 us; speedup 1.0000x reference)
//
#include <hip/hip_runtime.h>
#include <math.h>

#define BB 16
#define CC 256
#define TT 4096
#define NA 1024
#define NB 3072
#define OC 512

// ---------------- K1: per-token L2 norm over C ----------------
__global__ void k_norm(const float* __restrict__ x, float* __restrict__ norms) {
    int idx = blockIdx.x * 256 + threadIdx.x;   // b*TT + t
    int b = idx >> 12;
    int t = idx & 4095;
    const float* xp = x + (size_t)b * CC * TT + t;
    float s = 0.f;
#pragma unroll 8
    for (int c = 0; c < CC; ++c) {
        float v = xp[(size_t)c * TT];
        s = fmaf(v, v, s);
    }
    norms[idx] = sqrtf(s);
}

// ---------------- K2: transpose-pack normalized a/b tokens ----------------
// Ap[b][p][c] = x[b][c][4p]/norm,  Bp[b][j][c] = x[b][c][bidx(j)]/norm
__global__ void k_pack(const float* __restrict__ x, const float* __restrict__ norms,
                       float* __restrict__ Ap, float* __restrict__ Bp) {
    __shared__ float tile[64][65];
    __shared__ float ns[64];
    int b = blockIdx.z, c0 = blockIdx.y * 64, t0 = blockIdx.x * 64;
    int tid = threadIdx.x;
#pragma unroll
    for (int rep = 0; rep < 16; ++rep) {
        int lin = rep * 256 + tid;
        int i = lin >> 6, j = lin & 63;
        tile[i][j] = x[((size_t)b * CC + c0 + i) * TT + t0 + j];
    }
    if (tid < 64) ns[tid] = norms[b * TT + t0 + tid];
    __syncthreads();
#pragma unroll
    for (int rep = 0; rep < 16; ++rep) {
        int lin = rep * 256 + tid;
        int j = lin >> 6, i = lin & 63;   // j = token-in-tile, i = channel-in-tile
        int t = t0 + j;
        float v = tile[i][j] / ns[j];
        if ((t & 3) == 0) {
            Ap[((size_t)b * NA + (t >> 2)) * CC + c0 + i] = v;
        } else {
            int g = t >> 2, r = t & 3;
            Bp[((size_t)b * NB + 3 * g + (r - 1)) * CC + c0 + i] = v;
        }
    }
}

// ---------------- K3: argmax over 3072 b-tokens of cosine sim ----------------
// 64 a-rows per block, 64x64 tiles, 4x4 per thread, K=256 in steps of 16.
__global__ void __launch_bounds__(256) k_argmax(const float* __restrict__ Ap,
                                                const float* __restrict__ Bp,
                                                int* __restrict__ sel) {
    __shared__ float As[16][68];
    __shared__ float Bs[16][68];
    __shared__ float bvs[64][16];
    __shared__ int   bis[64][16];
    int b = blockIdx.y;
    int i0 = blockIdx.x * 64;
    int tid = threadIdx.x;
    int tr = tid >> 4, tc = tid & 15;
    int sr = tid >> 2, skb = (tid & 3) * 4;
    const float* Abase = Ap + (size_t)b * NA * CC + (size_t)i0 * CC;
    const float* Bbase = Bp + (size_t)b * NB * CC;

    float bestv[4];
    int besti[4];
#pragma unroll
    for (int u = 0; u < 4; ++u) { bestv[u] = -1e30f; besti[u] = 0; }

    for (int jt = 0; jt < NB / 64; ++jt) {
        float acc[4][4];
#pragma unroll
        for (int u = 0; u < 4; ++u)
#pragma unroll
            for (int v = 0; v < 4; ++v) acc[u][v] = 0.f;

        for (int kt = 0; kt < CC / 16; ++kt) {
            __syncthreads();
            float4 a4 = *(const float4*)(Abase + (size_t)sr * CC + kt * 16 + skb);
            float4 b4 = *(const float4*)(Bbase + (size_t)(jt * 64 + sr) * CC + kt * 16 + skb);
            As[skb + 0][sr] = a4.x; As[skb + 1][sr] = a4.y;
            As[skb + 2][sr] = a4.z; As[skb + 3][sr] = a4.w;
            Bs[skb + 0][sr] = b4.x; Bs[skb + 1][sr] = b4.y;
            Bs[skb + 2][sr] = b4.z; Bs[skb + 3][sr] = b4.w;
            __syncthreads();
#pragma unroll
            for (int kk = 0; kk < 16; ++kk) {
                float4 av = *(const float4*)&As[kk][tr * 4];
                float4 bv4 = *(const float4*)&Bs[kk][tc * 4];
                float a_[4] = {av.x, av.y, av.z, av.w};
                float b_[4] = {bv4.x, bv4.y, bv4.z, bv4.w};
#pragma unroll
                for (int u = 0; u < 4; ++u)
#pragma unroll
                    for (int v = 0; v < 4; ++v)
                        acc[u][v] = fmaf(a_[u], b_[v], acc[u][v]);
            }
        }
        // per-thread argmax update (ascending j; strict > keeps first occurrence)
#pragma unroll
        for (int u = 0; u < 4; ++u)
#pragma unroll
            for (int v = 0; v < 4; ++v) {
                int j = jt * 64 + tc * 4 + v;
                if (acc[u][v] > bestv[u]) { bestv[u] = acc[u][v]; besti[u] = j; }
            }
    }
    __syncthreads();
#pragma unroll
    for (int u = 0; u < 4; ++u) { bvs[tr * 4 + u][tc] = bestv[u]; bis[tr * 4 + u][tc] = besti[u]; }
    __syncthreads();
    if (tid < 64) {
        float bv = bvs[tid][0];
        int bi = bis[tid][0];
#pragma unroll
        for (int q = 1; q < 16; ++q) {
            float v = bvs[tid][q]; int ji = bis[tid][q];
            if (v > bv || (v == bv && ji < bi)) { bv = v; bi = ji; }
        }
        int g = bi / 3, r = bi - 3 * g;
        sel[b * NA + i0 + tid] = 4 * g + r + 1;   // linear token index of chosen b
    }
}

// ---------------- K4a: fuse (sim-merge + spatial-merge), write F[b][c][p] ----------------
__global__ void k_fuse(const float* __restrict__ x, const int* __restrict__ sel,
                       const float* __restrict__ fwraw, float* __restrict__ F) {
    int b = blockIdx.y;
    int p = blockIdx.x * 256 + threadIdx.x;
    float w0 = fminf(fmaxf(fwraw[0], 0.f), 6.f);
    float w1 = fminf(fmaxf(fwraw[1], 0.f), 6.f);
    float s = w0 + w1 + 1e-8f;
    float fw0 = w0 / s, fw1 = w1 / s;
    int lin = 4 * p;
    int col = lin & 63;
    int spa = (col == 0) ? lin + 1 : lin - 1;   // np.argmax first-tie ⇒ i-1 when col>0
    int ssim = sel[b * NA + p];
    const float* xb_ = x + (size_t)b * CC * TT;
    float* Fb = F + (size_t)b * CC * NA;
    for (int c = 0; c < CC; ++c) {
        const float* xr = xb_ + (size_t)c * TT;
        float xa = xr[lin], xs = xr[ssim], xp = xr[spa];
        float ms = (xa + xs) * 0.5f;
        float mp = (xa + xp) * 0.5f;
        Fb[(size_t)c * NA + p] = fw0 * ms + fw1 * mp;
    }
}

// ---------------- K4b: 1x1 conv GEMM + BN + SiLU ----------------
__global__ void __launch_bounds__(256) k_conv(const float* __restrict__ F, const float* __restrict__ W,
                                              const float* __restrict__ gamma, const float* __restrict__ beta,
                                              const float* __restrict__ mean, const float* __restrict__ var,
                                              float* __restrict__ out) {
    __shared__ float Ws[16][68];
    __shared__ float Fs[16][68];
    int b = blockIdx.z;
    int o0 = blockIdx.y * 64;
    int p0 = blockIdx.x * 64;
    int tid = threadIdx.x;
    int tr = tid >> 4, tc = tid & 15;
    int sr = tid >> 2, skb = (tid & 3) * 4;
    int fkk = tid >> 4, fj = (tid & 15) * 4;
    const float* Fb = F + (size_t)b * CC * NA;
    float acc[4][4];
#pragma unroll
    for (int u = 0; u < 4; ++u)
#pragma unroll
        for (int v = 0; v < 4; ++v) acc[u][v] = 0.f;

    for (int kt = 0; kt < CC / 16; ++kt) {
        __syncthreads();
        float4 w4 = *(const float4*)(W + (size_t)(o0 + sr) * CC + kt * 16 + skb);
        Ws[skb + 0][sr] = w4.x; Ws[skb + 1][sr] = w4.y;
        Ws[skb + 2][sr] = w4.z; Ws[skb + 3][sr] = w4.w;
        float4 f4 = *(const float4*)(Fb + (size_t)(kt * 16 + fkk) * NA + p0 + fj);
        *(float4*)&Fs[fkk][fj] = f4;
        __syncthreads();
#pragma unroll
        for (int kk = 0; kk < 16; ++kk) {
            float4 av = *(const float4*)&Ws[kk][tr * 4];
            float4 bv4 = *(const float4*)&Fs[kk][tc * 4];
            float a_[4] = {av.x, av.y, av.z, av.w};
            float b_[4] = {bv4.x, bv4.y, bv4.z, bv4.w};
#pragma unroll
            for (int u = 0; u < 4; ++u)
#pragma unroll
                for (int v = 0; v < 4; ++v)
                    acc[u][v] = fmaf(a_[u], b_[v], acc[u][v]);
        }
    }
#pragma unroll
    for (int u = 0; u < 4; ++u) {
        int o = o0 + tr * 4 + u;
        float sc = gamma[o] / sqrtf(var[o] + 1e-5f);
        float sh = fmaf(-mean[o], sc, beta[o]);
        float4 r;
        float* rp = &r.x;
#pragma unroll
        for (int v = 0; v < 4; ++v) {
            float y = fmaf(acc[u][v], sc, sh);
            rp[v] = y / (1.f + expf(-y));
        }
        *(float4*)(out + ((size_t)b * OC + o) * NA + p0 + tc * 4) = r;
    }
}

extern "C" void kernel_launch(void* const* d_in, const int* in_sizes, int n_in,
                              void* d_out, int out_size, void* d_ws, size_t ws_size,
                              hipStream_t stream) {
    const float* x      = (const float*)d_in[0];
    const float* conv_w = (const float*)d_in[1];
    const float* gamma  = (const float*)d_in[2];
    const float* beta   = (const float*)d_in[3];
    const float* mean   = (const float*)d_in[4];
    const float* var    = (const float*)d_in[5];
    const float* fw     = (const float*)d_in[6];
    float* out = (float*)d_out;

    float* ws    = (float*)d_ws;
    float* norms = ws;                          // BB*TT
    float* Ap    = norms + (size_t)BB * TT;     // BB*NA*CC
    float* Bp    = Ap + (size_t)BB * NA * CC;   // BB*NB*CC
    int*   sel   = (int*)(Bp + (size_t)BB * NB * CC);  // BB*NA ints
    float* F     = Ap;                          // reuse Ap region as F[b][c][p]

    k_norm<<<BB * TT / 256, 256, 0, stream>>>(x, norms);
    k_pack<<<dim3(TT / 64, CC / 64, BB), 256, 0, stream>>>(x, norms, Ap, Bp);
    k_argmax<<<dim3(NA / 64, BB), 256, 0, stream>>>(Ap, Bp, sel);
    k_fuse<<<dim3(NA / 256, BB), 256, 0, stream>>>(x, sel, fw, F);
    k_conv<<<dim3(NA / 64, OC / 64, BB), 256, 0, stream>>>(F, conv_w, gamma, beta, mean, var, out);
}

// Round 5
// 495.576 us; speedup vs baseline: 1.5760x; 1.5760x over previous
//
#include <hip/hip_runtime.h>
#include <math.h>

#define BB 16
#define CC 256
#define TT 4096
#define NA 1024
#define NB 3072
#define OC 512

#define NCHUNK 6   // j-chunks (each 512 b-cols = 4 j-tiles of 128)

// ---------------- K1: per-token L2 norm over C ----------------
__global__ void k_norm(const float* __restrict__ x, float* __restrict__ norms) {
    int idx = blockIdx.x * 256 + threadIdx.x;   // b*TT + t
    int b = idx >> 12;
    int t = idx & 4095;
    const float* xp = x + (size_t)b * CC * TT + t;
    float s = 0.f;
#pragma unroll 8
    for (int c = 0; c < CC; ++c) {
        float v = xp[(size_t)c * TT];
        s = fmaf(v, v, s);
    }
    norms[idx] = sqrtf(s);
}

// ---------------- K2: transpose-pack normalized a/b tokens ----------------
__global__ void k_pack(const float* __restrict__ x, const float* __restrict__ norms,
                       float* __restrict__ Ap, float* __restrict__ Bp) {
    __shared__ float tile[64][65];
    __shared__ float ns[64];
    int b = blockIdx.z, c0 = blockIdx.y * 64, t0 = blockIdx.x * 64;
    int tid = threadIdx.x;
#pragma unroll
    for (int rep = 0; rep < 16; ++rep) {
        int lin = rep * 256 + tid;
        int i = lin >> 6, j = lin & 63;
        tile[i][j] = x[((size_t)b * CC + c0 + i) * TT + t0 + j];
    }
    if (tid < 64) ns[tid] = norms[b * TT + t0 + tid];
    __syncthreads();
#pragma unroll
    for (int rep = 0; rep < 16; ++rep) {
        int lin = rep * 256 + tid;
        int j = lin >> 6, i = lin & 63;
        int t = t0 + j;
        float v = tile[i][j] / ns[j];
        if ((t & 3) == 0) {
            Ap[((size_t)b * NA + (t >> 2)) * CC + c0 + i] = v;
        } else {
            int g = t >> 2, r = t & 3;
            Bp[((size_t)b * NB + 3 * g + (r - 1)) * CC + c0 + i] = v;
        }
    }
}

// ---------------- K3: partial argmax, 128x128 tiles, 8x8/thread, j-chunked ----------------
__global__ void __launch_bounds__(256) k_argmax2(const float* __restrict__ Ap,
                                                 const float* __restrict__ Bp,
                                                 float* __restrict__ Pval,
                                                 int* __restrict__ Pidx) {
    __shared__ float smem[4224];           // As[16][132] | Bs[16][132]
    float* As = smem;
    float* Bs = smem + 2112;
    int b = blockIdx.z, ch = blockIdx.y;
    int i0 = blockIdx.x * 128;
    int tid = threadIdx.x;
    int tr = tid >> 4, tc = tid & 15;
    const float* Abase = Ap + ((size_t)b * NA + i0) * CC;
    const float* Bbase = Bp + (size_t)b * NB * CC;

    float bestv[8];
    int besti[8];
#pragma unroll
    for (int u = 0; u < 8; ++u) { bestv[u] = -1e30f; besti[u] = 0; }

    for (int jt = 0; jt < 4; ++jt) {
        int j0 = ch * 512 + jt * 128;
        float acc[8][8];
#pragma unroll
        for (int u = 0; u < 8; ++u)
#pragma unroll
            for (int v = 0; v < 8; ++v) acc[u][v] = 0.f;

        for (int kt = 0; kt < CC / 16; ++kt) {
            __syncthreads();
#pragma unroll
            for (int rep = 0; rep < 2; ++rep) {
                int lin = rep * 256 + tid;
                int r = lin >> 2, q = lin & 3;
                float4 a4 = *(const float4*)(Abase + (size_t)r * CC + kt * 16 + q * 4);
                float4 b4 = *(const float4*)(Bbase + (size_t)(j0 + r) * CC + kt * 16 + q * 4);
                As[(q * 4 + 0) * 132 + r] = a4.x; As[(q * 4 + 1) * 132 + r] = a4.y;
                As[(q * 4 + 2) * 132 + r] = a4.z; As[(q * 4 + 3) * 132 + r] = a4.w;
                Bs[(q * 4 + 0) * 132 + r] = b4.x; Bs[(q * 4 + 1) * 132 + r] = b4.y;
                Bs[(q * 4 + 2) * 132 + r] = b4.z; Bs[(q * 4 + 3) * 132 + r] = b4.w;
            }
            __syncthreads();
#pragma unroll
            for (int kk = 0; kk < 16; ++kk) {
                float4 a0 = *(const float4*)&As[kk * 132 + tr * 8];
                float4 a1 = *(const float4*)&As[kk * 132 + tr * 8 + 4];
                float4 b0 = *(const float4*)&Bs[kk * 132 + tc * 8];
                float4 b1 = *(const float4*)&Bs[kk * 132 + tc * 8 + 4];
                float a_[8] = {a0.x, a0.y, a0.z, a0.w, a1.x, a1.y, a1.z, a1.w};
                float b_[8] = {b0.x, b0.y, b0.z, b0.w, b1.x, b1.y, b1.z, b1.w};
#pragma unroll
                for (int u = 0; u < 8; ++u)
#pragma unroll
                    for (int v = 0; v < 8; ++v)
                        acc[u][v] = fmaf(a_[u], b_[v], acc[u][v]);
            }
        }
        // argmax update; ascending j, strict > keeps first occurrence
#pragma unroll
        for (int u = 0; u < 8; ++u)
#pragma unroll
            for (int v = 0; v < 8; ++v) {
                int j = j0 + tc * 8 + v;
                if (acc[u][v] > bestv[u]) { bestv[u] = acc[u][v]; besti[u] = j; }
            }
    }
    __syncthreads();
    float* bvs = smem;                 // [128][16]
    int* bis = (int*)(smem + 2112);    // [128][16]
#pragma unroll
    for (int u = 0; u < 8; ++u) {
        bvs[(tr * 8 + u) * 16 + tc] = bestv[u];
        bis[(tr * 8 + u) * 16 + tc] = besti[u];
    }
    __syncthreads();
    if (tid < 128) {
        float bv = bvs[tid * 16];
        int bi = bis[tid * 16];
#pragma unroll
        for (int q = 1; q < 16; ++q) {
            float v = bvs[tid * 16 + q];
            int ji = bis[tid * 16 + q];
            if (v > bv || (v == bv && ji < bi)) { bv = v; bi = ji; }
        }
        size_t o = ((size_t)b * NCHUNK + ch) * NA + i0 + tid;
        Pval[o] = bv;
        Pidx[o] = bi;
    }
}

// ---------------- K3b: reduce chunk partials -> sel ----------------
__global__ void k_reduce(const float* __restrict__ Pval, const int* __restrict__ Pidx,
                         int* __restrict__ sel) {
    int idx = blockIdx.x * 256 + threadIdx.x;   // b*NA + a
    int b = idx >> 10;
    int a = idx & 1023;
    float bv = -1e30f;
    int bi = 0;
#pragma unroll
    for (int ch = 0; ch < NCHUNK; ++ch) {
        size_t o = ((size_t)b * NCHUNK + ch) * NA + a;
        float v = Pval[o];
        int ji = Pidx[o];
        if (v > bv || (v == bv && ji < bi)) { bv = v; bi = ji; }
    }
    int g = bi / 3, r = bi - 3 * g;
    sel[idx] = 4 * g + r + 1;
}

// ---------------- K4a: fuse (sim-merge + spatial-merge), write F[b][c][p] ----------------
__global__ void k_fuse(const float* __restrict__ x, const int* __restrict__ sel,
                       const float* __restrict__ fwraw, float* __restrict__ F) {
    int b = blockIdx.y;
    int p = blockIdx.x * 256 + threadIdx.x;
    float w0 = fminf(fmaxf(fwraw[0], 0.f), 6.f);
    float w1 = fminf(fmaxf(fwraw[1], 0.f), 6.f);
    float s = w0 + w1 + 1e-8f;
    float fw0 = w0 / s, fw1 = w1 / s;
    int lin = 4 * p;
    int col = lin & 63;
    int spa = (col == 0) ? lin + 1 : lin - 1;
    int ssim = sel[b * NA + p];
    const float* xb_ = x + (size_t)b * CC * TT;
    float* Fb = F + (size_t)b * CC * NA;
    for (int c = 0; c < CC; ++c) {
        const float* xr = xb_ + (size_t)c * TT;
        float xa = xr[lin], xs = xr[ssim], xp = xr[spa];
        float ms = (xa + xs) * 0.5f;
        float mp = (xa + xp) * 0.5f;
        Fb[(size_t)c * NA + p] = fw0 * ms + fw1 * mp;
    }
}

// ---------------- K4b: 1x1 conv GEMM + BN + SiLU ----------------
__global__ void __launch_bounds__(256) k_conv(const float* __restrict__ F, const float* __restrict__ W,
                                              const float* __restrict__ gamma, const float* __restrict__ beta,
                                              const float* __restrict__ mean, const float* __restrict__ var,
                                              float* __restrict__ out) {
    __shared__ float Ws[16][68];
    __shared__ float Fs[16][68];
    int b = blockIdx.z;
    int o0 = blockIdx.y * 64;
    int p0 = blockIdx.x * 64;
    int tid = threadIdx.x;
    int tr = tid >> 4, tc = tid & 15;
    int sr = tid >> 2, skb = (tid & 3) * 4;
    int fkk = tid >> 4, fj = (tid & 15) * 4;
    const float* Fb = F + (size_t)b * CC * NA;
    float acc[4][4];
#pragma unroll
    for (int u = 0; u < 4; ++u)
#pragma unroll
        for (int v = 0; v < 4; ++v) acc[u][v] = 0.f;

    for (int kt = 0; kt < CC / 16; ++kt) {
        __syncthreads();
        float4 w4 = *(const float4*)(W + (size_t)(o0 + sr) * CC + kt * 16 + skb);
        Ws[skb + 0][sr] = w4.x; Ws[skb + 1][sr] = w4.y;
        Ws[skb + 2][sr] = w4.z; Ws[skb + 3][sr] = w4.w;
        float4 f4 = *(const float4*)(Fb + (size_t)(kt * 16 + fkk) * NA + p0 + fj);
        *(float4*)&Fs[fkk][fj] = f4;
        __syncthreads();
#pragma unroll
        for (int kk = 0; kk < 16; ++kk) {
            float4 av = *(const float4*)&Ws[kk][tr * 4];
            float4 bv4 = *(const float4*)&Fs[kk][tc * 4];
            float a_[4] = {av.x, av.y, av.z, av.w};
            float b_[4] = {bv4.x, bv4.y, bv4.z, bv4.w};
#pragma unroll
            for (int u = 0; u < 4; ++u)
#pragma unroll
                for (int v = 0; v < 4; ++v)
                    acc[u][v] = fmaf(a_[u], b_[v], acc[u][v]);
        }
    }
#pragma unroll
    for (int u = 0; u < 4; ++u) {
        int o = o0 + tr * 4 + u;
        float sc = gamma[o] / sqrtf(var[o] + 1e-5f);
        float sh = fmaf(-mean[o], sc, beta[o]);
        float4 r;
        float* rp = &r.x;
#pragma unroll
        for (int v = 0; v < 4; ++v) {
            float y = fmaf(acc[u][v], sc, sh);
            rp[v] = y / (1.f + expf(-y));
        }
        *(float4*)(out + ((size_t)b * OC + o) * NA + p0 + tc * 4) = r;
    }
}

extern "C" void kernel_launch(void* const* d_in, const int* in_sizes, int n_in,
                              void* d_out, int out_size, void* d_ws, size_t ws_size,
                              hipStream_t stream) {
    const float* x      = (const float*)d_in[0];
    const float* conv_w = (const float*)d_in[1];
    const float* gamma  = (const float*)d_in[2];
    const float* beta   = (const float*)d_in[3];
    const float* mean   = (const float*)d_in[4];
    const float* var    = (const float*)d_in[5];
    const float* fw     = (const float*)d_in[6];
    float* out = (float*)d_out;

    float* ws    = (float*)d_ws;
    float* norms = ws;                                   // BB*TT
    float* Ap    = norms + (size_t)BB * TT;              // BB*NA*CC
    float* Bp    = Ap + (size_t)BB * NA * CC;            // BB*NB*CC
    float* Pval  = Bp + (size_t)BB * NB * CC;            // BB*NCHUNK*NA
    int*   Pidx  = (int*)(Pval + (size_t)BB * NCHUNK * NA);
    int*   sel   = (int*)(Pidx + (size_t)BB * NCHUNK * NA);
    float* F     = Ap;                                   // reuse Ap region as F[b][c][p]

    k_norm<<<BB * TT / 256, 256, 0, stream>>>(x, norms);
    k_pack<<<dim3(TT / 64, CC / 64, BB), 256, 0, stream>>>(x, norms, Ap, Bp);
    k_argmax2<<<dim3(NA / 128, NCHUNK, BB), 256, 0, stream>>>(Ap, Bp, Pval, Pidx);
    k_reduce<<<BB * NA / 256, 256, 0, stream>>>(Pval, Pidx, sel);
    k_fuse<<<dim3(NA / 256, BB), 256, 0, stream>>>(x, sel, fw, F);
    k_conv<<<dim3(NA / 64, OC / 64, BB), 256, 0, stream>>>(F, conv_w, gamma, beta, mean, var, out);
}

// Round 6
// 483.483 us; speedup vs baseline: 1.6154x; 1.0250x over previous
//
#include <hip/hip_runtime.h>
#include <math.h>

#define BB 16
#define CC 256
#define TT 4096
#define NA 1024
#define NB 3072
#define OC 512

#define NCHUNK 12   // j-chunks (each 256 b-cols = 2 j-tiles of 128)

// ---------------- K1: per-token L2 norm over C ----------------
__global__ void k_norm(const float* __restrict__ x, float* __restrict__ norms) {
    int idx = blockIdx.x * 256 + threadIdx.x;   // b*TT + t
    int b = idx >> 12;
    int t = idx & 4095;
    const float* xp = x + (size_t)b * CC * TT + t;
    float s = 0.f;
#pragma unroll 8
    for (int c = 0; c < CC; ++c) {
        float v = xp[(size_t)c * TT];
        s = fmaf(v, v, s);
    }
    norms[idx] = sqrtf(s);
}

// ---------------- K2: transpose-pack normalized a/b tokens ----------------
__global__ void k_pack(const float* __restrict__ x, const float* __restrict__ norms,
                       float* __restrict__ Ap, float* __restrict__ Bp) {
    __shared__ float tile[64][65];
    __shared__ float ns[64];
    int b = blockIdx.z, c0 = blockIdx.y * 64, t0 = blockIdx.x * 64;
    int tid = threadIdx.x;
#pragma unroll
    for (int rep = 0; rep < 16; ++rep) {
        int lin = rep * 256 + tid;
        int i = lin >> 6, j = lin & 63;
        tile[i][j] = x[((size_t)b * CC + c0 + i) * TT + t0 + j];
    }
    if (tid < 64) ns[tid] = norms[b * TT + t0 + tid];
    __syncthreads();
#pragma unroll
    for (int rep = 0; rep < 16; ++rep) {
        int lin = rep * 256 + tid;
        int j = lin >> 6, i = lin & 63;
        int t = t0 + j;
        float v = tile[i][j] / ns[j];
        if ((t & 3) == 0) {
            Ap[((size_t)b * NA + (t >> 2)) * CC + c0 + i] = v;
        } else {
            int g = t >> 2, r = t & 3;
            Bp[((size_t)b * NB + 3 * g + (r - 1)) * CC + c0 + i] = v;
        }
    }
}

// ---------------- K3: partial argmax, 128x128 tiles, 8x8/thread, j-chunked ----------------
// B-fragment read mapping: thread tc owns j = {tc*4..tc*4+3} U {64+tc*4..64+tc*4+3}
// -> 16 lane addresses span a contiguous 256B (2-way bank aliasing, free) instead of
//    the 4-way conflict of the tc*8 mapping.
__global__ void __launch_bounds__(256) k_argmax2(const float* __restrict__ Ap,
                                                 const float* __restrict__ Bp,
                                                 float* __restrict__ Pval,
                                                 int* __restrict__ Pidx) {
    __shared__ float smem[4224];           // As[16][132] | Bs[16][132]
    float* As = smem;
    float* Bs = smem + 2112;
    int b = blockIdx.z, ch = blockIdx.y;
    int i0 = blockIdx.x * 128;
    int tid = threadIdx.x;
    int tr = tid >> 4, tc = tid & 15;
    const float* Abase = Ap + ((size_t)b * NA + i0) * CC;
    const float* Bbase = Bp + (size_t)b * NB * CC;

    float bestv[8];
    int besti[8];
#pragma unroll
    for (int u = 0; u < 8; ++u) { bestv[u] = -1e30f; besti[u] = 0; }

    for (int jt = 0; jt < 2; ++jt) {
        int j0 = ch * 256 + jt * 128;
        float acc[8][8];
#pragma unroll
        for (int u = 0; u < 8; ++u)
#pragma unroll
            for (int v = 0; v < 8; ++v) acc[u][v] = 0.f;

        for (int kt = 0; kt < CC / 16; ++kt) {
            __syncthreads();
#pragma unroll
            for (int rep = 0; rep < 2; ++rep) {
                int lin = rep * 256 + tid;
                int r = lin >> 2, q = lin & 3;
                float4 a4 = *(const float4*)(Abase + (size_t)r * CC + kt * 16 + q * 4);
                float4 b4 = *(const float4*)(Bbase + (size_t)(j0 + r) * CC + kt * 16 + q * 4);
                As[(q * 4 + 0) * 132 + r] = a4.x; As[(q * 4 + 1) * 132 + r] = a4.y;
                As[(q * 4 + 2) * 132 + r] = a4.z; As[(q * 4 + 3) * 132 + r] = a4.w;
                Bs[(q * 4 + 0) * 132 + r] = b4.x; Bs[(q * 4 + 1) * 132 + r] = b4.y;
                Bs[(q * 4 + 2) * 132 + r] = b4.z; Bs[(q * 4 + 3) * 132 + r] = b4.w;
            }
            __syncthreads();
#pragma unroll
            for (int kk = 0; kk < 16; ++kk) {
                float4 a0 = *(const float4*)&As[kk * 132 + tr * 8];
                float4 a1 = *(const float4*)&As[kk * 132 + tr * 8 + 4];
                float4 b0 = *(const float4*)&Bs[kk * 132 + tc * 4];
                float4 b1 = *(const float4*)&Bs[kk * 132 + 64 + tc * 4];
                float a_[8] = {a0.x, a0.y, a0.z, a0.w, a1.x, a1.y, a1.z, a1.w};
                float b_[8] = {b0.x, b0.y, b0.z, b0.w, b1.x, b1.y, b1.z, b1.w};
#pragma unroll
                for (int u = 0; u < 8; ++u)
#pragma unroll
                    for (int v = 0; v < 8; ++v)
                        acc[u][v] = fmaf(a_[u], b_[v], acc[u][v]);
            }
        }
        // argmax update; per-thread j ascending (tc*4+v then 64+tc*4+v), strict >
#pragma unroll
        for (int u = 0; u < 8; ++u)
#pragma unroll
            for (int v = 0; v < 8; ++v) {
                int j = j0 + (v < 4 ? tc * 4 + v : 64 + tc * 4 + (v - 4));
                if (acc[u][v] > bestv[u]) { bestv[u] = acc[u][v]; besti[u] = j; }
            }
    }
    __syncthreads();
    float* bvs = smem;                 // [128][16]
    int* bis = (int*)(smem + 2112);    // [128][16]
#pragma unroll
    for (int u = 0; u < 8; ++u) {
        bvs[(tr * 8 + u) * 16 + tc] = bestv[u];
        bis[(tr * 8 + u) * 16 + tc] = besti[u];
    }
    __syncthreads();
    if (tid < 128) {
        float bv = bvs[tid * 16];
        int bi = bis[tid * 16];
#pragma unroll
        for (int q = 1; q < 16; ++q) {
            float v = bvs[tid * 16 + q];
            int ji = bis[tid * 16 + q];
            if (v > bv || (v == bv && ji < bi)) { bv = v; bi = ji; }
        }
        size_t o = ((size_t)b * NCHUNK + ch) * NA + i0 + tid;
        Pval[o] = bv;
        Pidx[o] = bi;
    }
}

// ---------------- K3b: reduce chunk partials -> sel ----------------
__global__ void k_reduce(const float* __restrict__ Pval, const int* __restrict__ Pidx,
                         int* __restrict__ sel) {
    int idx = blockIdx.x * 256 + threadIdx.x;   // b*NA + a
    int b = idx >> 10;
    int a = idx & 1023;
    float bv = -1e30f;
    int bi = 0x7fffffff;
#pragma unroll
    for (int ch = 0; ch < NCHUNK; ++ch) {
        size_t o = ((size_t)b * NCHUNK + ch) * NA + a;
        float v = Pval[o];
        int ji = Pidx[o];
        if (v > bv || (v == bv && ji < bi)) { bv = v; bi = ji; }
    }
    int g = bi / 3, r = bi - 3 * g;
    sel[idx] = 4 * g + r + 1;
}

// ---------------- K4a: fuse (sim-merge + spatial-merge), write F[b][c][p] ----------------
__global__ void k_fuse(const float* __restrict__ x, const int* __restrict__ sel,
                       const float* __restrict__ fwraw, float* __restrict__ F) {
    int b = blockIdx.y;
    int p = blockIdx.x * 256 + threadIdx.x;
    float w0 = fminf(fmaxf(fwraw[0], 0.f), 6.f);
    float w1 = fminf(fmaxf(fwraw[1], 0.f), 6.f);
    float s = w0 + w1 + 1e-8f;
    float fw0 = w0 / s, fw1 = w1 / s;
    int lin = 4 * p;
    int col = lin & 63;
    int spa = (col == 0) ? lin + 1 : lin - 1;
    int ssim = sel[b * NA + p];
    const float* xb_ = x + (size_t)b * CC * TT;
    float* Fb = F + (size_t)b * CC * NA;
    for (int c = 0; c < CC; ++c) {
        const float* xr = xb_ + (size_t)c * TT;
        float xa = xr[lin], xs = xr[ssim], xp = xr[spa];
        float ms = (xa + xs) * 0.5f;
        float mp = (xa + xp) * 0.5f;
        Fb[(size_t)c * NA + p] = fw0 * ms + fw1 * mp;
    }
}

// ---------------- K4b: 1x1 conv GEMM + BN + SiLU ----------------
__global__ void __launch_bounds__(256) k_conv(const float* __restrict__ F, const float* __restrict__ W,
                                              const float* __restrict__ gamma, const float* __restrict__ beta,
                                              const float* __restrict__ mean, const float* __restrict__ var,
                                              float* __restrict__ out) {
    __shared__ float Ws[16][68];
    __shared__ float Fs[16][68];
    int b = blockIdx.z;
    int o0 = blockIdx.y * 64;
    int p0 = blockIdx.x * 64;
    int tid = threadIdx.x;
    int tr = tid >> 4, tc = tid & 15;
    int sr = tid >> 2, skb = (tid & 3) * 4;
    int fkk = tid >> 4, fj = (tid & 15) * 4;
    const float* Fb = F + (size_t)b * CC * NA;
    float acc[4][4];
#pragma unroll
    for (int u = 0; u < 4; ++u)
#pragma unroll
        for (int v = 0; v < 4; ++v) acc[u][v] = 0.f;

    for (int kt = 0; kt < CC / 16; ++kt) {
        __syncthreads();
        float4 w4 = *(const float4*)(W + (size_t)(o0 + sr) * CC + kt * 16 + skb);
        Ws[skb + 0][sr] = w4.x; Ws[skb + 1][sr] = w4.y;
        Ws[skb + 2][sr] = w4.z; Ws[skb + 3][sr] = w4.w;
        float4 f4 = *(const float4*)(Fb + (size_t)(kt * 16 + fkk) * NA + p0 + fj);
        *(float4*)&Fs[fkk][fj] = f4;
        __syncthreads();
#pragma unroll
        for (int kk = 0; kk < 16; ++kk) {
            float4 av = *(const float4*)&Ws[kk][tr * 4];
            float4 bv4 = *(const float4*)&Fs[kk][tc * 4];
            float a_[4] = {av.x, av.y, av.z, av.w};
            float b_[4] = {bv4.x, bv4.y, bv4.z, bv4.w};
#pragma unroll
            for (int u = 0; u < 4; ++u)
#pragma unroll
                for (int v = 0; v < 4; ++v)
                    acc[u][v] = fmaf(a_[u], b_[v], acc[u][v]);
        }
    }
#pragma unroll
    for (int u = 0; u < 4; ++u) {
        int o = o0 + tr * 4 + u;
        float sc = gamma[o] / sqrtf(var[o] + 1e-5f);
        float sh = fmaf(-mean[o], sc, beta[o]);
        float4 r;
        float* rp = &r.x;
#pragma unroll
        for (int v = 0; v < 4; ++v) {
            float y = fmaf(acc[u][v], sc, sh);
            rp[v] = y / (1.f + expf(-y));
        }
        *(float4*)(out + ((size_t)b * OC + o) * NA + p0 + tc * 4) = r;
    }
}

extern "C" void kernel_launch(void* const* d_in, const int* in_sizes, int n_in,
                              void* d_out, int out_size, void* d_ws, size_t ws_size,
                              hipStream_t stream) {
    const float* x      = (const float*)d_in[0];
    const float* conv_w = (const float*)d_in[1];
    const float* gamma  = (const float*)d_in[2];
    const float* beta   = (const float*)d_in[3];
    const float* mean   = (const float*)d_in[4];
    const float* var    = (const float*)d_in[5];
    const float* fw     = (const float*)d_in[6];
    float* out = (float*)d_out;

    float* ws    = (float*)d_ws;
    float* norms = ws;                                   // BB*TT
    float* Ap    = norms + (size_t)BB * TT;              // BB*NA*CC
    float* Bp    = Ap + (size_t)BB * NA * CC;            // BB*NB*CC
    float* Pval  = Bp + (size_t)BB * NB * CC;            // BB*NCHUNK*NA
    int*   Pidx  = (int*)(Pval + (size_t)BB * NCHUNK * NA);
    int*   sel   = (int*)(Pidx + (size_t)BB * NCHUNK * NA);
    float* F     = Ap;                                   // reuse Ap region as F[b][c][p]

    k_norm<<<BB * TT / 256, 256, 0, stream>>>(x, norms);
    k_pack<<<dim3(TT / 64, CC / 64, BB), 256, 0, stream>>>(x, norms, Ap, Bp);
    k_argmax2<<<dim3(NA / 128, NCHUNK, BB), 256, 0, stream>>>(Ap, Bp, Pval, Pidx);
    k_reduce<<<BB * NA / 256, 256, 0, stream>>>(Pval, Pidx, sel);
    k_fuse<<<dim3(NA / 256, BB), 256, 0, stream>>>(x, sel, fw, F);
    k_conv<<<dim3(NA / 64, OC / 64, BB), 256, 0, stream>>>(F, conv_w, gamma, beta, mean, var, out);
}